// Round 6
// baseline (737.013 us; speedup 1.0000x reference)
//
#include <hip/hip_runtime.h>
#include <hip/hip_bf16.h>
#include <cstdint>
#include <cstddef>

// ---------- types ----------
typedef __attribute__((ext_vector_type(8))) short    bf16x8;   // 8 bf16 = 4 VGPRs (MFMA A/B frag)
typedef __attribute__((ext_vector_type(4))) float    f32x4;    // MFMA C/D frag
typedef __attribute__((ext_vector_type(8))) unsigned short u16x8;
typedef __attribute__((ext_vector_type(4))) float    f32v4;
typedef __attribute__((ext_vector_type(4))) unsigned short u16v4;

__device__ __forceinline__ float b2f(unsigned short v) {
    return __builtin_bit_cast(float, ((unsigned int)v) << 16);
}
__device__ __forceinline__ unsigned short f2b(float f) {
    unsigned int u = __builtin_bit_cast(unsigned int, f);
    u += 0x7fffu + ((u >> 16) & 1u);        // RNE
    return (unsigned short)(u >> 16);
}

__device__ __forceinline__ void async16(const void* g, void* l) {
    __builtin_amdgcn_global_load_lds(
        (const __attribute__((address_space(1))) unsigned int*)g,
        (__attribute__((address_space(3))) unsigned int*)l, 16, 0, 0);
}

// ---------- f32 -> bf16 convert (two buffers in one dispatch) ----------
__global__ __launch_bounds__(256) void cvt2_f32_bf16(
    const float* __restrict__ srcA, unsigned short* __restrict__ dstA, int n4A,
    const float* __restrict__ srcB, unsigned short* __restrict__ dstB, int n4B) {
    int i = blockIdx.x * blockDim.x + threadIdx.x;
    int stride = gridDim.x * blockDim.x;
    const int nTot = n4A + n4B;
    for (; i < nTot; i += stride) {
        const bool inA = (i < n4A);
        const f32v4* s4 = inA ? (const f32v4*)srcA : (const f32v4*)srcB;
        u16v4* d4 = inA ? (u16v4*)dstA : (u16v4*)dstB;
        const int k = inA ? i : (i - n4A);
        f32v4 v = s4[k];
        u16v4 o;
        o.x = f2b(v.x); o.y = f2b(v.y); o.z = f2b(v.z); o.w = f2b(v.w);
        d4[k] = o;
    }
}

__global__ __launch_bounds__(256) void cvt_f32_bf16(const float* __restrict__ src,
                                                    unsigned short* __restrict__ dst, int n4) {
    int i = blockIdx.x * blockDim.x + threadIdx.x;
    int stride = gridDim.x * blockDim.x;
    const f32v4* s4 = (const f32v4*)src;
    u16v4* d4 = (u16v4*)dst;
    for (; i < n4; i += stride) {
        f32v4 v = s4[i];
        u16v4 o;
        o.x = f2b(v.x); o.y = f2b(v.y); o.z = f2b(v.z); o.w = f2b(v.w);
        d4[i] = o;
    }
}

// ============ 256x256-tile 8-phase bf16 MFMA GEMM (m201-style schedule) ============
// C[m][n] = sum_k A[m][k]*Bw[n][k] + bias[n]
// 512 threads = 8 waves (2 M x 4 N); per-wave C = 128x64 = acc[8][4] f32x4.
// BK=64; LDS double-buffered by K-tile parity: buf b at b*65536: A 32KB @0, B 32KB @32768.
// A LDS row order permutes 64-row blocks {0,2,1,3} so half h0 = rows read by quads 0-1.
// XOR swizzle: LDS[L][u] holds global unit u^(L&7) (pre-swizzled global source, linear dest).
// Block->tile map (r4): XCD x = bid&7 owns by-stripe [4x,4x+4); within-stripe order gives
// 8bx x 4by supertiles so the ~32 concurrent blocks/XCD share an 8 MiB B + 4 MiB A working
// set (halves L2-miss refetch vs row-major chunks). Requires nby==32, ntn in {8,16,24}.
// Schedule per iteration (2 K-tiles t0=2i buf0, t1=2i+1 buf1), 8 phases:
//   P1: LDB(0)+LDA(0,q0) | stage A(t1)h1            P5: LDB(1)+LDA(1,q0) | stage A(t0+2)h1
//   P2: LDA(0,q1)        | stage B(t0+2)h0          P6: LDA(1,q1)        | stage B(t1+2)h0
//   P3: LDA(0,q2)        | stage B(t0+2)h1          P7: LDA(1,q2)        | stage B(t1+2)h1
//   P4: LDA(0,q3)        | stage A(t0+2)h0 +vmcnt6  P8: LDA(1,q3)        | stage A(t1+2)h0 +vmcnt6
// vmcnt(6) at P4 drains through P1's loads, at P8 drains through P5's. Last iter: vmcnt(0).
// MODE 0: Cout = float row-major [M][N].  MODE 1: bf16 u-layout Cout[(bI*CH+n)*Lseq+l].
template <int MODE>
__global__ __launch_bounds__(512, 1) void gemm256(
    const unsigned short* __restrict__ A,   // M x K bf16 row-major
    const unsigned short* __restrict__ Bw,  // N x K bf16 row-major
    const float* __restrict__ bias,         // N
    void* __restrict__ Cout,
    int M, int N, int K, int Lseq, int CH, int ntn)
{
    constexpr int SMEM_BYTES = (MODE == 1) ? 135168 : 131072;   // epi needs 256*264*2
    __shared__ char smemc[SMEM_BYTES];

    const int tid = threadIdx.x;
    const int w   = tid >> 6;           // wave 0..7
    const int l   = tid & 63;
    const int wm  = w & 1;              // 2 waves in M
    const int wn  = w >> 1;             // 4 waves in N
    const int quad = l >> 4;
    const int lq   = l & 15;

    // XCD supertile remap (bijective: bid <-> (x, j&7, (j>>3)&3, j>>5))
    const int bid = blockIdx.x;
    const int x  = bid & 7;
    const int j  = bid >> 3;
    const int bx = (j & 7) + 8 * (j >> 5);
    const int by = (x << 2) | ((j >> 3) & 3);
    const int n0 = bx * 256, m0 = by * 256;

    // swizzled ds_read unit indices (global k-unit kk*4+quad lives at LDS unit ^ (row&7))
    const int su0 = quad ^ (lq & 7);
    const int su1 = su0 ^ 4;

    // staging: per wave 2 insts per (operand, half); lane fetches pre-swizzled global unit
    uint32_t offAe[2][2], offBe[2][2];
    int dA[2][2], dB[2][2];
    #pragma unroll
    for (int h = 0; h < 2; ++h)
        #pragma unroll
        for (int c = 0; c < 2; ++c) {
            const int Lr = h * 128 + w * 16 + c * 8 + (l >> 3);
            const int gA = ((Lr & 64) << 1) | ((Lr & 128) >> 1) | (Lr & 63);  // block perm {0,2,1,3}
            const int u  = (l & 7) ^ (l >> 3);
            offAe[h][c] = (uint32_t)(m0 + gA) * (uint32_t)K + (uint32_t)(u * 8);
            offBe[h][c] = (uint32_t)(n0 + Lr) * (uint32_t)K + (uint32_t)(u * 8);
            const int rb = (h * 128 + w * 16 + c * 8) * 128;   // LDS byte row base (wave-uniform)
            dA[h][c] = rb;
            dB[h][c] = 32768 + rb;
        }

#define STAGE_A(bs, h, tile) do { \
    async16(A + offAe[h][0] + (size_t)(tile) * 64, smemc + ((bs) * 65536 + dA[h][0])); \
    async16(A + offAe[h][1] + (size_t)(tile) * 64, smemc + ((bs) * 65536 + dA[h][1])); \
} while (0)
#define STAGE_B(bs, h, tile) do { \
    async16(Bw + offBe[h][0] + (size_t)(tile) * 64, smemc + ((bs) * 65536 + dB[h][0])); \
    async16(Bw + offBe[h][1] + (size_t)(tile) * 64, smemc + ((bs) * 65536 + dB[h][1])); \
} while (0)

    f32x4 acc[8][4] = {};
    bf16x8 bw[4][2], a[2][2];

#define LDB8(bs) do { \
    _Pragma("unroll") for (int jj = 0; jj < 4; ++jj) { \
        const int Lr = wn * 64 + jj * 16 + lq; \
        bw[jj][0] = *(const bf16x8*)(smemc + (bs) * 65536 + 32768 + Lr * 128 + su0 * 16); \
        bw[jj][1] = *(const bf16x8*)(smemc + (bs) * 65536 + 32768 + Lr * 128 + su1 * 16); \
    } } while (0)
#define LDA4(bs, q) do { \
    _Pragma("unroll") for (int mf = 0; mf < 2; ++mf) { \
        const int g = wm * 128 + (q) * 32 + mf * 16 + lq; \
        const int Lr = ((g & 64) << 1) | ((g & 128) >> 1) | (g & 63); \
        a[mf][0] = *(const bf16x8*)(smemc + (bs) * 65536 + Lr * 128 + su0 * 16); \
        a[mf][1] = *(const bf16x8*)(smemc + (bs) * 65536 + Lr * 128 + su1 * 16); \
    } } while (0)
#define MFMA16(q) do { \
    _Pragma("unroll") for (int mf = 0; mf < 2; ++mf) \
    _Pragma("unroll") for (int jj = 0; jj < 4; ++jj) \
    _Pragma("unroll") for (int kk = 0; kk < 2; ++kk) \
        acc[(q) * 2 + mf][jj] = __builtin_amdgcn_mfma_f32_16x16x32_bf16(a[mf][kk], bw[jj][kk], acc[(q) * 2 + mf][jj], 0, 0, 0); \
} while (0)
#define PHASE_SYNC() do { \
    __builtin_amdgcn_s_barrier(); \
    asm volatile("s_waitcnt lgkmcnt(0)" ::: "memory"); \
    __builtin_amdgcn_sched_barrier(0); \
    __builtin_amdgcn_s_setprio(1); \
} while (0)
#define PHASE_END() do { \
    __builtin_amdgcn_s_setprio(0); \
    __builtin_amdgcn_s_barrier(); \
} while (0)
#define PHASE_END_DRAIN(lastf) do { \
    __builtin_amdgcn_s_setprio(0); \
    if (lastf) asm volatile("s_waitcnt vmcnt(0)" ::: "memory"); \
    else       asm volatile("s_waitcnt vmcnt(6)" ::: "memory"); \
    __builtin_amdgcn_s_barrier(); \
} while (0)

    // prologue: tile0 full + tile1 all-but-Ah1 (14 loads/wave); drain tile0, keep 6 in flight
    STAGE_B(0, 0, 0); STAGE_B(0, 1, 0); STAGE_A(0, 0, 0); STAGE_A(0, 1, 0);
    STAGE_B(1, 0, 1); STAGE_B(1, 1, 1); STAGE_A(1, 0, 1);
    asm volatile("s_waitcnt vmcnt(6)" ::: "memory");
    __builtin_amdgcn_s_barrier();

    const int nIt = K >> 7;             // 2 K-tiles (BK=64) per iteration
    for (int i = 0; i < nIt; ++i) {
        const bool last = (i == nIt - 1);
        const int t0 = 2 * i, t1 = 2 * i + 1;
        // P1
        LDB8(0); LDA4(0, 0); STAGE_A(1, 1, t1);
        PHASE_SYNC(); MFMA16(0); PHASE_END();
        // P2
        LDA4(0, 1); if (!last) STAGE_B(0, 0, t0 + 2);
        PHASE_SYNC(); MFMA16(1); PHASE_END();
        // P3
        LDA4(0, 2); if (!last) STAGE_B(0, 1, t0 + 2);
        PHASE_SYNC(); MFMA16(2); PHASE_END();
        // P4
        LDA4(0, 3); if (!last) STAGE_A(0, 0, t0 + 2);
        PHASE_SYNC(); MFMA16(3); PHASE_END_DRAIN(last);
        // P5
        LDB8(1); LDA4(1, 0); if (!last) STAGE_A(0, 1, t0 + 2);
        PHASE_SYNC(); MFMA16(0); PHASE_END();
        // P6
        LDA4(1, 1); if (!last) STAGE_B(1, 0, t1 + 2);
        PHASE_SYNC(); MFMA16(1); PHASE_END();
        // P7
        LDA4(1, 2); if (!last) STAGE_B(1, 1, t1 + 2);
        PHASE_SYNC(); MFMA16(2); PHASE_END();
        // P8
        LDA4(1, 3); if (!last) STAGE_A(1, 0, t1 + 2);
        PHASE_SYNC(); MFMA16(3); PHASE_END_DRAIN(last);
    }

    if (MODE == 0) {
        float* out = (float*)Cout;
        #pragma unroll
        for (int jj = 0; jj < 4; ++jj) {
            const int col = n0 + wn * 64 + jj * 16 + lq;
            const float bv = bias[col];
            #pragma unroll
            for (int i8 = 0; i8 < 8; ++i8) {
                const int rowb = m0 + wm * 128 + i8 * 16 + quad * 4;
                f32x4 c = acc[i8][jj];
                out[(size_t)(rowb + 0) * N + col] = c.x + bv;
                out[(size_t)(rowb + 1) * N + col] = c.y + bv;
                out[(size_t)(rowb + 2) * N + col] = c.z + bv;
                out[(size_t)(rowb + 3) * N + col] = c.w + bv;
            }
        }
    } else {
        // transpose through LDS (alias staging buffers; loop fully drained at last PHASE_END_DRAIN)
        unsigned short* sE = (unsigned short*)smemc;   // [256][264]
        __syncthreads();
        #pragma unroll
        for (int jj = 0; jj < 4; ++jj) {
            const int nl = wn * 64 + jj * 16 + lq;
            const float bv = bias[n0 + nl];
            #pragma unroll
            for (int i8 = 0; i8 < 8; ++i8) {
                const int ml = wm * 128 + i8 * 16 + quad * 4;
                f32x4 c = acc[i8][jj];
                u16v4 pk;
                pk.x = f2b(c.x + bv); pk.y = f2b(c.y + bv);
                pk.z = f2b(c.z + bv); pk.w = f2b(c.w + bv);
                *(u16v4*)&sE[nl * 264 + ml] = pk;
            }
        }
        __syncthreads();
        unsigned short* uo = (unsigned short*)Cout;
        const int bI = m0 >> 12;        // 4096 rows per batch (M-tiles never straddle)
        const int l0 = m0 & 4095;
        for (int e = tid; e < 8192; e += 512) {
            const int nl = e >> 5, seg = e & 31;
            u16x8 v = *(const u16x8*)&sE[nl * 264 + seg * 8];
            *(u16x8*)&uo[(size_t)(bI * CH + n0 + nl) * Lseq + l0 + seg * 8] = v;
        }
    }
#undef STAGE_A
#undef STAGE_B
#undef LDB8
#undef LDA4
#undef MFMA16
#undef PHASE_SYNC
#undef PHASE_END
#undef PHASE_END_DRAIN
}

// ---------- Hyena filter k(D,L) ----------
__global__ __launch_bounds__(256) void filter_kernel(
    const float* __restrict__ w0, const float* __restrict__ b0,
    const float* __restrict__ freq,
    const float* __restrict__ w1, const float* __restrict__ b1,
    const float* __restrict__ w2, const float* __restrict__ b2,
    const float* __restrict__ w3, float* __restrict__ kf)
{
    __shared__ float ha[64][64];
    __shared__ float hb[64][64];
    const int tid = threadIdx.x;
    const int l0 = blockIdx.x * 64;
    const int d0 = blockIdx.y * 256;
    const int l  = tid & 63;
    const int lg = l0 + l;
    const float tt = (float)lg * (1.0f / 4095.0f);
    const float wang = 6.283185307179586f * (float)lg * (1.0f / 4096.0f);
    const float a  = 1e-4f * wang;
    const float z0 = tt, z1 = cosf(a), z2 = -sinf(a);

    for (int e = tid; e < 4096; e += 256) {
        const int dim = e >> 6;
        float pre = z0 * w0[dim * 3] + z1 * w0[dim * 3 + 1] + z2 * w0[dim * 3 + 2] + b0[dim];
        ha[dim][l] = sinf(freq[dim] * pre);
    }
    __syncthreads();
    for (int e = tid; e < 4096; e += 256) {
        const int dim = e >> 6;
        float acc = b1[dim];
        #pragma unroll
        for (int jj = 0; jj < 64; ++jj) acc += w1[dim * 64 + jj] * ha[jj][l];
        hb[dim][l] = sinf(freq[dim] * acc);
    }
    __syncthreads();
    for (int e = tid; e < 4096; e += 256) {
        const int dim = e >> 6;
        float acc = b2[dim];
        #pragma unroll
        for (int jj = 0; jj < 64; ++jj) acc += w2[dim * 64 + jj] * hb[jj][l];
        ha[dim][l] = sinf(freq[dim] * acc);
    }
    __syncthreads();
    for (int d = d0 + (tid >> 6); d < d0 + 256; d += 4) {
        float acc = 0.f;
        #pragma unroll
        for (int jj = 0; jj < 64; ++jj) acc += w3[d * 64 + jj] * ha[jj][l];
        // deltas = linspace(ln(.01)/1.5, ln(.01)/0.3, 2048); decay = exp(-t*|delta|)
        const float delta = fabsf(-3.0701134573253944f + (-5.999245642062483e-3f) * (float)d);
        kf[(size_t)d * 4096 + lg] = acc * __expf(-tt * delta);
    }
}

// ================= register-resident 8192-pt FFT (512 thr, 16 pts/thr) =================
// Ownerships: A: p = t + 512 s | B: p = (t>>5)*512 + (t&31) + 32 s | C: p = 16 t + j
// DIF forward ends bit-reversed-contiguous (C); inverse DIT consumes C and ends at A.
// LDS pad: +4 floats per 32 (PIDX) -> preserves 16B alignment of 8/16-aligned runs, so the
// C-side xchg and 8-contig conv I/O use ds_{read,write}_b128; all patterns stay <=2-way banked.
#define PIDX(i) ((i) + (((i) >> 5) << 2))

__device__ __forceinline__ void bfly_f(float& r1, float& i1, float& r2, float& i2, float wr, float wi) {
    float ur = r1, ui = i1, vr = r2, vi = i2;
    r1 = ur + vr; i1 = ui + vi;
    float dr = ur - vr, di = ui - vi;
    r2 = dr * wr - di * wi;
    i2 = dr * wi + di * wr;
}
__device__ __forceinline__ void bfly_i(float& r1, float& i1, float& r2, float& i2, float wr, float wi) {
    float vr = r2 * wr - i2 * wi, vi = r2 * wi + i2 * wr;
    float ur = r1, ui = i1;
    r1 = ur + vr; i1 = ui + vi;
    r2 = ur - vr; i2 = ui - vi;
}

// stage hm = STR*DS; j = tt + STR*(s mod DS); theta = -pi*j/hm (fwd) / +pi*j/hm (inv)
template <int DS, int STR>
__device__ __forceinline__ void fwd_stage(float* re, float* im, int tt) {
    float wr[8], wi[8];
    constexpr float c = -3.14159265358979f / (float)(STR * DS);
    #pragma unroll
    for (int k = 0; k < DS; ++k) __sincosf(c * (float)(tt + STR * k), &wi[k], &wr[k]);
    #pragma unroll
    for (int s = 0; s < 16; ++s)
        if ((s & DS) == 0)
            bfly_f(re[s], im[s], re[s + DS], im[s + DS], wr[s & (DS - 1)], wi[s & (DS - 1)]);
}
template <int DS, int STR>
__device__ __forceinline__ void inv_stage(float* re, float* im, int tt) {
    float wr[8], wi[8];
    constexpr float c = 3.14159265358979f / (float)(STR * DS);
    #pragma unroll
    for (int k = 0; k < DS; ++k) __sincosf(c * (float)(tt + STR * k), &wi[k], &wr[k]);
    #pragma unroll
    for (int s = 0; s < 16; ++s)
        if ((s & DS) == 0)
            bfly_i(re[s], im[s], re[s + DS], im[s + DS], wr[s & (DS - 1)], wi[s & (DS - 1)]);
}

// STR==1 stages (tt==0): twiddles are compile-time constants cos/sin(k*pi/DS) -> literal
// table indexed at k*(8/DS); avoids ~15 runtime __sincosf per direction per thread.
__device__ constexpr float TW8C[8] = { 1.f,  0.9238795325112867f,  0.7071067811865476f,  0.3826834323650898f,
                                       0.f, -0.3826834323650898f, -0.7071067811865476f, -0.9238795325112867f };
__device__ constexpr float TW8S[8] = { 0.f,  0.3826834323650898f,  0.7071067811865476f,  0.9238795325112867f,
                                       1.f,  0.9238795325112867f,  0.7071067811865476f,  0.3826834323650898f };
template <int DS>
__device__ __forceinline__ void fwd_stageC(float* re, float* im) {
    #pragma unroll
    for (int s = 0; s < 16; ++s)
        if ((s & DS) == 0) {
            const int k = (s & (DS - 1)) * (8 / DS);
            bfly_f(re[s], im[s], re[s + DS], im[s + DS], TW8C[k], -TW8S[k]);
        }
}
template <int DS>
__device__ __forceinline__ void inv_stageC(float* re, float* im) {
    #pragma unroll
    for (int s = 0; s < 16; ++s)
        if ((s & DS) == 0) {
            const int k = (s & (DS - 1)) * (8 / DS);
            bfly_i(re[s], im[s], re[s + DS], im[s + DS], TW8C[k], TW8S[k]);
        }
}

// xchg: wstr==1 / rstr==1 (C-ownership side) vectorize to 4x b128 (16t is 16-aligned; the
// +4/32 pad keeps any 4-run inside one 32-segment contiguous and 16B-aligned).
__device__ __forceinline__ void xchg(float* re, float* im, float* fre, float* fim,
                                     int wbase, int wstr, int rbase, int rstr) {
    __syncthreads();           // protect prior reads of fre/fim
    if (wstr == 1) {
        #pragma unroll
        for (int q = 0; q < 4; ++q) {
            f32x4 vr, vi;
            vr.x = re[4*q+0]; vr.y = re[4*q+1]; vr.z = re[4*q+2]; vr.w = re[4*q+3];
            vi.x = im[4*q+0]; vi.y = im[4*q+1]; vi.z = im[4*q+2]; vi.w = im[4*q+3];
            *(f32x4*)&fre[PIDX(wbase + 4*q)] = vr;
            *(f32x4*)&fim[PIDX(wbase + 4*q)] = vi;
        }
    } else {
        #pragma unroll
        for (int s = 0; s < 16; ++s) {
            const int i = wbase + wstr * s;
            fre[PIDX(i)] = re[s]; fim[PIDX(i)] = im[s];
        }
    }
    __syncthreads();
    if (rstr == 1) {
        #pragma unroll
        for (int q = 0; q < 4; ++q) {
            f32x4 vr = *(const f32x4*)&fre[PIDX(rbase + 4*q)];
            f32x4 vi = *(const f32x4*)&fim[PIDX(rbase + 4*q)];
            re[4*q+0] = vr.x; re[4*q+1] = vr.y; re[4*q+2] = vr.z; re[4*q+3] = vr.w;
            im[4*q+0] = vi.x; im[4*q+1] = vi.y; im[4*q+2] = vi.z; im[4*q+3] = vi.w;
        }
    } else {
        #pragma unroll
        for (int s = 0; s < 16; ++s) {
            const int i = rbase + rstr * s;
            re[s] = fre[PIDX(i)]; im[s] = fim[PIDX(i)];
        }
    }
}

__device__ __forceinline__ void fwd_fft(float* re, float* im, float* fre, float* fim, int t) {
    const int off = t & 31, seg = t >> 5;
    fwd_stage<8, 512>(re, im, t);
    fwd_stage<4, 512>(re, im, t);
    fwd_stage<2, 512>(re, im, t);
    fwd_stage<1, 512>(re, im, t);
    xchg(re, im, fre, fim, t, 512, seg * 512 + off, 32);        // A -> B
    fwd_stage<8, 32>(re, im, off);
    fwd_stage<4, 32>(re, im, off);
    fwd_stage<2, 32>(re, im, off);
    fwd_stage<1, 32>(re, im, off);
    {   // hm = 16 (m = 32) across threads t ^ 16; j = off & 15 (thread-constant)
        float wr, wi;
        __sincosf(-3.14159265358979f * (float)(off & 15) / 16.0f, &wi, &wr);
        const bool hi = (off & 16) != 0;
        #pragma unroll
        for (int s = 0; s < 16; ++s) {
            float rr = __shfl_xor(re[s], 16);
            float ri = __shfl_xor(im[s], 16);
            if (!hi) { re[s] += rr; im[s] += ri; }
            else {
                float dr = rr - re[s], di = ri - im[s];
                re[s] = dr * wr - di * wi;
                im[s] = dr * wi + di * wr;
            }
        }
    }
    xchg(re, im, fre, fim, seg * 512 + off, 32, 16 * t, 1);     // B -> C
    fwd_stageC<8>(re, im);
    fwd_stageC<4>(re, im);
    fwd_stageC<2>(re, im);
    fwd_stageC<1>(re, im);
}

__device__ __forceinline__ void inv_fft(float* re, float* im, float* fre, float* fim, int t) {
    const int off = t & 31, seg = t >> 5;
    inv_stageC<1>(re, im);
    inv_stageC<2>(re, im);
    inv_stageC<4>(re, im);
    inv_stageC<8>(re, im);
    xchg(re, im, fre, fim, 16 * t, 1, seg * 512 + off, 32);     // C -> B
    {   // hm = 16 (m = 32), conj twiddle; v' = W * x[p+16]
        float wr, wi;
        __sincosf(3.14159265358979f * (float)(off & 15) / 16.0f, &wi, &wr);
        const bool hi = (off & 16) != 0;
        #pragma unroll
        for (int s = 0; s < 16; ++s) {
            float rr = __shfl_xor(re[s], 16);
            float ri = __shfl_xor(im[s], 16);
            if (!hi) {           // u = own, v' = W * recv
                float vr = rr * wr - ri * wi, vi = rr * wi + ri * wr;
                re[s] += vr; im[s] += vi;
            } else {             // u = recv, v' = W * own
                float vr = re[s] * wr - im[s] * wi, vi = re[s] * wi + im[s] * wr;
                re[s] = rr - vr; im[s] = ri - vi;
            }
        }
    }
    inv_stage<1, 32>(re, im, off);
    inv_stage<2, 32>(re, im, off);
    inv_stage<4, 32>(re, im, off);
    inv_stage<8, 32>(re, im, off);
    xchg(re, im, fre, fim, seg * 512 + off, 32, t, 512);        // B -> A
    inv_stage<1, 512>(re, im, t);
    inv_stage<2, 512>(re, im, t);
    inv_stage<4, 512>(re, im, t);
    inv_stage<8, 512>(re, im, t);
}

// ---------- causal 3-tap depthwise conv helpers (prefetch / compute split) ----------
struct ConvPre { u16x8 v; float m1, m2; };
__device__ __forceinline__ ConvPre conv_pre(const unsigned short* __restrict__ row, int lb) {
    ConvPre p;
    p.v  = *(const u16x8*)(row + lb);
    p.m1 = (lb >= 1) ? b2f(row[lb - 1]) : 0.f;
    p.m2 = (lb >= 2) ? b2f(row[lb - 2]) : 0.f;
    return p;
}
__device__ __forceinline__ void conv_do(const ConvPre& p,
                                        float W0, float W1, float W2, float BB,
                                        float* __restrict__ out) {
    float f[8];
    #pragma unroll
    for (int j = 0; j < 8; ++j) f[j] = b2f((unsigned short)p.v[j]);
    out[0] = W0 * p.m2 + W1 * p.m1 + W2 * f[0] + BB;
    out[1] = W0 * p.m1 + W1 * f[0] + W2 * f[1] + BB;
    #pragma unroll
    for (int j = 2; j < 8; ++j) out[j] = W0 * f[j - 2] + W1 * f[j - 1] + W2 * f[j] + BB;
}

// ---------- fused: K-FFT + short conv + gate + fftconv + bias + x0 gate -> zb ----------
// K spectrum lives in 32 REGISTERS (kr/ki, C ownership) - no LDS park, no global round trip
// (r0's LDS park cost occupancy; r1-r5's kspec buffer cost 256 MiB HBM + a kernel).
// Register discipline: x0's conv is NOT kept live through the FFTs - c0 rows are prefetched
// before the IFFT and the conv recomputed at the epilogue, keeping the live set at the
// r5-proven profile (xr/xi + kr/ki + vgc + temps <= 128 VGPR, arg2=2 -> 2 blocks/CU).
// Phase-1 u loads are prefetched BEFORE the K-FFT so HBM latency hides under it (T14).
__global__ __launch_bounds__(512, 2) void hyena_fft_kernel(
    const unsigned short* __restrict__ u,   // (B, 3D, L) bf16
    const float* __restrict__ kf,           // (D, L) f32 filter
    const float* __restrict__ sw,           // (3D, 1, 3)
    const float* __restrict__ sbv,          // (3D)
    const float* __restrict__ fbias,        // (D)
    unsigned short* __restrict__ zb)        // (B, D, L) bf16
{
    __shared__ __align__(16) float fre[9216];
    __shared__ __align__(16) float fim[9216];
    const int t = threadIdx.x;
    const int d = blockIdx.x;
    const int lb = t << 3;

    const int c0 = d, c1 = 2048 + d, c2 = 4096 + d;
    const float w10 = sw[c1*3+0], w11 = sw[c1*3+1], w12 = sw[c1*3+2], bb1 = sbv[c1];
    const float w20 = sw[c2*3+0], w21 = sw[c2*3+1], w22 = sw[c2*3+2], bb2 = sbv[c2];
    const float fb = fbias[d];

    // ---- prefetch phase-1 conv inputs (c1, c2 rows, both batches) before the K-FFT ----
    ConvPre p1[2], p2[2];
    #pragma unroll
    for (int b = 0; b < 2; ++b) {
        const size_t base = (size_t)b * 6144 * 4096;
        p1[b] = conv_pre(u + base + (size_t)c1 * 4096, lb);
        p2[b] = conv_pre(u + base + (size_t)c2 * 4096, lb);
    }

    // ---- K-FFT: spectrum stays in registers (C ownership = exactly what the multiply needs) ----
    float kr[16], ki[16];
    #pragma unroll
    for (int s = 0; s < 16; ++s) {
        kr[s] = (s < 8) ? kf[(size_t)d * 4096 + t + 512 * s] : 0.f;
        ki[s] = 0.f;
    }
    fwd_fft(kr, ki, fre, fim, t);

    // ---- conv + gating -> vg (16 regs, live through both FFTs) ----
    float vgc[2][8];
    #pragma unroll
    for (int b = 0; b < 2; ++b) {
        float e_[8], g_[8];
        conv_do(p1[b], w10, w11, w12, bb1, e_);
        conv_do(p2[b], w20, w21, w22, bb2, g_);
        #pragma unroll
        for (int j = 0; j < 8; ++j) vgc[b][j] = g_[j] * e_[j];
    }

    // ---- redistribute vg (8-contig -> A ownership); barrier protects K-FFT's tail LDS reads ----
    __syncthreads();
    #pragma unroll
    for (int q = 0; q < 2; ++q) {
        f32x4 vr, vi;
        vr.x = vgc[0][4*q+0]; vr.y = vgc[0][4*q+1]; vr.z = vgc[0][4*q+2]; vr.w = vgc[0][4*q+3];
        vi.x = vgc[1][4*q+0]; vi.y = vgc[1][4*q+1]; vi.z = vgc[1][4*q+2]; vi.w = vgc[1][4*q+3];
        *(f32x4*)&fre[PIDX(lb + 4*q)] = vr;
        *(f32x4*)&fim[PIDX(lb + 4*q)] = vi;
    }
    __syncthreads();
    float xr[16], xi[16];
    #pragma unroll
    for (int s = 0; s < 8; ++s) {
        xr[s] = fre[PIDX(t + (s << 9))];
        xi[s] = fim[PIDX(t + (s << 9))];
    }
    #pragma unroll
    for (int s = 8; s < 16; ++s) { xr[s] = 0.f; xi[s] = 0.f; }

    // ---- C = FFT(vg0 + i*vg1); pointwise *K in registers; inverse to A ----
    fwd_fft(xr, xi, fre, fim, t);    // leading __syncthreads protects redistribution reads
    #pragma unroll
    for (int j = 0; j < 16; ++j) {
        const float cr = xr[j], ci = xi[j];
        xr[j] = cr * kr[j] - ci * ki[j];
        xi[j] = cr * ki[j] + ci * kr[j];
    }

    // prefetch c0 rows for the epilogue conv; HBM latency hides under the IFFT
    ConvPre p0[2];
    #pragma unroll
    for (int b = 0; b < 2; ++b)
        p0[b] = conv_pre(u + (size_t)b * 6144 * 4096 + (size_t)c0 * 4096, lb);

    inv_fft(xr, xi, fre, fim, t);

    // ---- redistribute y (A -> 8-contig); epilogue recomputes x0 conv; u16x8 stores ----
    __syncthreads();                 // protect inv_fft's last xchg reads
    #pragma unroll
    for (int s = 0; s < 8; ++s) {
        fre[PIDX(t + (s << 9))] = xr[s];
        fim[PIDX(t + (s << 9))] = xi[s];
    }
    __syncthreads();
    float yr[8], yi[8];
    #pragma unroll
    for (int q = 0; q < 2; ++q) {
        f32x4 vr = *(const f32x4*)&fre[PIDX(lb + 4*q)];
        f32x4 vi = *(const f32x4*)&fim[PIDX(lb + 4*q)];
        yr[4*q+0] = vr.x; yr[4*q+1] = vr.y; yr[4*q+2] = vr.z; yr[4*q+3] = vr.w;
        yi[4*q+0] = vi.x; yi[4*q+1] = vi.y; yi[4*q+2] = vi.z; yi[4*q+3] = vi.w;
    }
    const float w00 = sw[c0*3+0], w01 = sw[c0*3+1], w02 = sw[c0*3+2], bb0 = sbv[c0];
    const float inv_n = 1.0f / 8192.0f;
    #pragma unroll
    for (int b = 0; b < 2; ++b) {
        float a_[8];
        conv_do(p0[b], w00, w01, w02, bb0, a_);
        const float* Y = (b == 0) ? yr : yi;
        u16x8 zv;
        #pragma unroll
        for (int j = 0; j < 8; ++j)
            zv[j] = (unsigned short)f2b((Y[j] * inv_n + vgc[b][j] * fb) * a_[j]);
        *(u16x8*)&zb[(size_t)(b * 2048 + d) * 4096 + lb] = zv;
    }
}

// ---------- (B,D,L) bf16 -> (B,L,D) bf16 transpose ----------
__global__ __launch_bounds__(256) void transpose_kernel(const unsigned short* __restrict__ zb,
                                                        unsigned short* __restrict__ zt)
{
    __shared__ unsigned int tile[64][65];
    const int l0 = blockIdx.x * 64, d0 = blockIdx.y * 64, b = blockIdx.z;
    const int tid = threadIdx.x;
    for (int e = tid; e < 4096; e += 256) {
        const int r = e >> 6, c = e & 63;  // r = d-local, c = l-local
        tile[r][c] = zb[(size_t)(b * 2048 + d0 + r) * 4096 + l0 + c];
    }
    __syncthreads();
    for (int e = tid; e < 4096; e += 256) {
        const int r = e >> 6, c = e & 63;  // r = l-local, c = d-local
        zt[(size_t)(b * 4096 + l0 + r) * 2048 + d0 + c] = (unsigned short)tile[c][r];
    }
}

// ---------- launch ----------
// Workspace lifetime plan (256 MiB total, kspec eliminated):
//   [0,32)    xb (cvt..gemm1) -> zbm (hyena..transpose)
//   [32,56)   wbi (cvt..gemm1) -> ztb (transpose..gemm2)   (wbi is [32,56), ztb [32,64) ok: see below)
//   [64,72)   wbo (cvt..gemm2)
//   [128,224) ub (gemm1..hyena)
//   [224,256) kf (filter..hyena)
// ztb actually occupies [32,64) (32 MiB); wbi [32,56) is dead before transpose writes ztb. Disjoint
// from wbo [64,72). All lifetimes verified non-overlapping in time.
extern "C" void kernel_launch(void* const* d_in, const int* in_sizes, int n_in,
                              void* d_out, int out_size, void* d_ws, size_t ws_size,
                              hipStream_t stream)
{
    const float* x   = (const float*)d_in[0];
    const float* ipw = (const float*)d_in[1];
    const float* ipb = (const float*)d_in[2];
    const float* sw  = (const float*)d_in[3];
    const float* sb  = (const float*)d_in[4];
    const float* w0  = (const float*)d_in[5];
    const float* b0  = (const float*)d_in[6];
    const float* fr  = (const float*)d_in[7];
    const float* w1  = (const float*)d_in[8];
    const float* b1  = (const float*)d_in[9];
    const float* w2  = (const float*)d_in[10];
    const float* b2  = (const float*)d_in[11];
    const float* w3  = (const float*)d_in[12];
    const float* fb  = (const float*)d_in[13];
    const float* opw = (const float*)d_in[14];
    const float* opb = (const float*)d_in[15];
    float* out = (float*)d_out;

    char* ws = (char*)d_ws;
    unsigned short* xb  = (unsigned short*)ws;                   // 32 MiB [0,32)
    unsigned short* wbi = (unsigned short*)(ws + 33554432);      // 24 MiB [32,56)
    unsigned short* zbm = (unsigned short*)ws;                   // 32 MiB [0,32)   (after gemm1)
    unsigned short* ztb = (unsigned short*)(ws + 33554432);      // 32 MiB [32,64)  (after hyena)
    unsigned short* wbo = (unsigned short*)(ws + 67108864);      // 8 MiB  [64,72)
    unsigned short* ub  = (unsigned short*)(ws + 134217728);     // 96 MiB [128,224)
    float*          kf  = (float*)(ws + 234881024);              // 32 MiB [224,256)

    cvt2_f32_bf16<<<1536, 256, 0, stream>>>(x, xb, 16777216 / 4, ipw, wbi, 12582912 / 4);

    // u = (x @ W_in^T + b) written transposed to (B, 3D, L); frees xb/wbi afterwards
    // grid = (8192/256) * (6144/256) = 32 * 24 = 768 (1D, XCD-supertile-swizzled in-kernel)
    gemm256<1><<<768, 512, 0, stream>>>(xb, wbi, ipb, ub, 8192, 6144, 2048, 4096, 6144, 24);

    filter_kernel<<<dim3(64, 8), 256, 0, stream>>>(w0, b0, fr, w1, b1, w2, b2, w3, kf);

    // out-proj weight convert (xb/wbi region dead after gemm1; wbo region disjoint)
    cvt_f32_bf16<<<512, 256, 0, stream>>>(opw, wbo, 4194304 / 4);

    // fused K-FFT + conv + gate + fftconv (kspec round trip eliminated)
    hyena_fft_kernel<<<2048, 512, 0, stream>>>(ub, kf, sw, sb, fb, zbm);

    transpose_kernel<<<dim3(64, 32, 2), 256, 0, stream>>>(zbm, ztb);

    // out = z @ W_out^T + b (f32); grid = 32 * 8 = 256
    gemm256<0><<<256, 512, 0, stream>>>(ztb, wbo, opb, out, 8192, 2048, 2048, 4096, 2048, 8);
}